// Round 8
// baseline (460.057 us; speedup 1.0000x reference)
//
#include <hip/hip_runtime.h>
#include <hip/hip_bf16.h>
#include <math.h>

typedef __hip_bfloat16 bf16;
typedef __attribute__((ext_vector_type(8))) short short8;
typedef __attribute__((ext_vector_type(4))) float f32x4;

__device__ __forceinline__ float b2f(bf16 v) { return __bfloat162float(v); }
__device__ __forceinline__ bf16 f2b(float f) { return __float2bfloat16(f); }

// ---------------------------------------------------------------------------
// K0: all 4 weight transposes (fp32 KxN -> bf16 NxK) in one launch.
// ---------------------------------------------------------------------------
__launch_bounds__(256)
__global__ void transpose_all(const float* __restrict__ qkv_w,
                              const float* __restrict__ proj_w,
                              const float* __restrict__ fc1_w,
                              const float* __restrict__ fc2_w,
                              bf16* __restrict__ qkv_wt,
                              bf16* __restrict__ proj_wt,
                              bf16* __restrict__ fc1_wt,
                              bf16* __restrict__ fc2_wt)
{
    __shared__ float t[32][33];
    int id = blockIdx.x;
    const float* W; bf16* Wt; int K, N, tix, tiy;
    if (id < 1728)      { W = qkv_w;  Wt = qkv_wt;  K = 768;  N = 2304; tix = id % 72;           tiy = id / 72; }
    else if (id < 2304) { W = proj_w; Wt = proj_wt; K = 768;  N = 768;  tix = (id - 1728) % 24;  tiy = (id - 1728) / 24; }
    else if (id < 4608) { W = fc1_w;  Wt = fc1_wt;  K = 768;  N = 3072; tix = (id - 2304) % 96;  tiy = (id - 2304) / 96; }
    else                { W = fc2_w;  Wt = fc2_wt;  K = 3072; N = 768;  tix = (id - 4608) % 24;  tiy = (id - 4608) / 24; }
    int n0 = tix * 32, k0 = tiy * 32;
    int tx = threadIdx.x & 31, ty = threadIdx.x >> 5;   // 32 x 8
    #pragma unroll
    for (int i = 0; i < 4; i++)
        t[ty * 4 + i][tx] = W[(size_t)(k0 + ty * 4 + i) * N + n0 + tx];
    __syncthreads();
    #pragma unroll
    for (int i = 0; i < 4; i++)
        Wt[(size_t)(n0 + ty * 4 + i) * K + k0 + tx] = f2b(t[tx][ty * 4 + i]);
}

// ---------------------------------------------------------------------------
// K0b: vt pad-fill (keys 196..223 zero everywhere; padded-window keys get
// v_bias); convert qkv_b -> bf16; build bf16 rel tables (32x64, rows>=27 = 0).
// ---------------------------------------------------------------------------
__launch_bounds__(256)
__global__ void fill_kernel(const float* __restrict__ qkv_b,
                            const float* __restrict__ rel_h,
                            const float* __restrict__ rel_w,
                            bf16* __restrict__ vt,
                            bf16* __restrict__ bias_bf,
                            bf16* __restrict__ rhb,
                            bf16* __restrict__ rwb)
{
    int blk = blockIdx.x;
    int tid = threadIdx.x;
    if (blk == 600) {
        for (int c = tid; c < 2304; c += 256) bias_bf[c] = f2b(qkv_b[c]);
        for (int idx = tid; idx < 2048; idx += 256) {
            int r = idx >> 6, c = idx & 63;
            rhb[idx] = (r < 27) ? f2b(rel_h[r * 64 + c]) : f2b(0.0f);
            rwb[idx] = (r < 27) ? f2b(rel_w[r * 64 + c]) : f2b(0.0f);
        }
        return;
    }
    int bwi = blk / 12, head = blk % 12;
    size_t base = (size_t)(bwi * 12 + head) * 64 * 224;
    // zero keys 196..223 for all rows (finite pad; P is zero there)
    for (int t = tid; t < 64 * 28; t += 256) {
        int d = t / 28, k = 196 + t % 28;
        vt[base + (size_t)d * 224 + k] = f2b(0.0f);
    }
    int wq = bwi % 25;
    int hi = ((wq / 5) == 4) ? 8 : 14;
    int wi = ((wq % 5) == 4) ? 8 : 14;
    if (hi == 14 && wi == 14) return;
    for (int t = tid; t < 196 * 64; t += 256) {
        int d = t & 63, key = t >> 6;
        int i = key / 14, j = key % 14;
        if (i >= hi || j >= wi)
            vt[base + (size_t)d * 224 + key] = f2b(qkv_b[1536 + head * 64 + d]);
    }
}

// ---------------------------------------------------------------------------
// K1/K5: LayerNorm (fp32 in, 768 cols) -> bf16 out.
// ---------------------------------------------------------------------------
__launch_bounds__(256)
__global__ void ln_kernel(const float* __restrict__ y,
                          const float* __restrict__ wgt,
                          const float* __restrict__ bia,
                          bf16* __restrict__ xn)
{
    int blk = blockIdx.x;
    const float* yin = y + (size_t)blk * 768;
    bf16* out = xn + (size_t)blk * 768;
    int tid = threadIdx.x;
    float v[3]; float s = 0.f, ss = 0.f;
    #pragma unroll
    for (int t = 0; t < 3; t++) {
        float f = yin[tid + t * 256];
        v[t] = f; s += f; ss += f * f;
    }
    #pragma unroll
    for (int o = 32; o > 0; o >>= 1) { s += __shfl_xor(s, o); ss += __shfl_xor(ss, o); }
    __shared__ float red[8];
    int w = tid >> 6, lane = tid & 63;
    if (lane == 0) { red[w] = s; red[4 + w] = ss; }
    __syncthreads();
    s  = red[0] + red[1] + red[2] + red[3];
    ss = red[4] + red[5] + red[6] + red[7];
    float mu = s * (1.0f / 768.0f);
    float var = ss * (1.0f / 768.0f) - mu * mu;
    float rs = rsqrtf(var + 1e-5f);
    #pragma unroll
    for (int t = 0; t < 3; t++) {
        int c = tid + t * 256;
        out[c] = f2b((v[t] - mu) * rs * wgt[c] + bia[c]);
    }
}

// ---------------------------------------------------------------------------
// MFMA GEMM: C = A(M x K) @ Bt^T + bias.  BK=64 (two BK=32 LDS buffers),
// XCD-aware swizzle (x-siblings share f%8 -> same XCD L2).  (unchanged)
// ---------------------------------------------------------------------------
template<int EPI, int BM>
__launch_bounds__(256)
__global__ void mfma_gemm(const bf16* __restrict__ A,
                          const bf16* __restrict__ Bt,
                          const float* __restrict__ bias,
                          bf16* __restrict__ outb,
                          float* __restrict__ outf,
                          const float* __restrict__ xres,
                          const float* __restrict__ yres,
                          bf16* __restrict__ vtg,
                          int M, int N, int K)
{
    constexpr int MI = BM / 32;
    __shared__ bf16 As0[BM * 32];
    __shared__ bf16 As1[BM * 32];
    __shared__ bf16 Bs0[128 * 32];
    __shared__ bf16 Bs1[128 * 32];
    const int tid = threadIdx.x;
    const int w = tid >> 6, lane = tid & 63;
    const int cl = lane & 15, rg = lane >> 4;
    const int wm = (w & 1) * (BM / 2), wn = (w >> 1) * 64;

    const int gx = gridDim.x;
    int f = blockIdx.x + gx * blockIdx.y;
    int g = f / (8 * gx), r8 = f % (8 * gx);
    const int tm = (g * 8 + (r8 & 7)) * BM;
    const int tn = (r8 >> 3) * 128;

    f32x4 acc[MI][4] = {};

    for (int k0 = 0; k0 < K; k0 += 64) {
        #pragma unroll
        for (int i = 0; i < BM / 64; i++) {
            int e = i * 256 + tid;
            int r = e >> 2, ch = e & 3;
            const bf16* ap = A + (size_t)(tm + r) * K + k0 + ch * 8;
            __builtin_amdgcn_global_load_lds(
                (const __attribute__((address_space(1))) unsigned*)(ap),
                (__attribute__((address_space(3))) unsigned*)(As0 + e * 8), 16, 0, 0);
            __builtin_amdgcn_global_load_lds(
                (const __attribute__((address_space(1))) unsigned*)(ap + 32),
                (__attribute__((address_space(3))) unsigned*)(As1 + e * 8), 16, 0, 0);
        }
        #pragma unroll
        for (int i = 0; i < 2; i++) {
            int e = i * 256 + tid;
            int r = e >> 2, ch = e & 3;
            const bf16* bp = Bt + (size_t)(tn + r) * K + k0 + ch * 8;
            __builtin_amdgcn_global_load_lds(
                (const __attribute__((address_space(1))) unsigned*)(bp),
                (__attribute__((address_space(3))) unsigned*)(Bs0 + e * 8), 16, 0, 0);
            __builtin_amdgcn_global_load_lds(
                (const __attribute__((address_space(1))) unsigned*)(bp + 32),
                (__attribute__((address_space(3))) unsigned*)(Bs1 + e * 8), 16, 0, 0);
        }
        __syncthreads();
        #pragma unroll
        for (int kk = 0; kk < 2; kk++) {
            const bf16* Ab = kk ? As1 : As0;
            const bf16* Bb = kk ? Bs1 : Bs0;
            short8 af[MI], bfr[4];
            #pragma unroll
            for (int mi = 0; mi < MI; mi++)
                af[mi] = *(const short8*)(Ab + (wm + mi * 16 + cl) * 32 + rg * 8);
            #pragma unroll
            for (int ni = 0; ni < 4; ni++)
                bfr[ni] = *(const short8*)(Bb + (wn + ni * 16 + cl) * 32 + rg * 8);
            #pragma unroll
            for (int mi = 0; mi < MI; mi++)
                #pragma unroll
                for (int ni = 0; ni < 4; ni++)
                    acc[mi][ni] = __builtin_amdgcn_mfma_f32_16x16x32_bf16(
                        af[mi], bfr[ni], acc[mi][ni], 0, 0, 0);
        }
        __syncthreads();
    }

    const int row_l = rg * 4;
    float bv[4];
    #pragma unroll
    for (int ni = 0; ni < 4; ni++) bv[ni] = bias[tn + wn + ni * 16 + cl];

    #pragma unroll
    for (int mi = 0; mi < MI; mi++) {
        #pragma unroll
        for (int r = 0; r < 4; r++) {
            int gm = tm + wm + mi * 16 + row_l + r;
            if (EPI == 0) {
                int bb = gm >> 12, rr = (gm >> 6) & 63, cc = gm & 63;
                int wh = rr / 14, ii = rr - wh * 14;
                int ww2 = cc / 14, jj = cc - ww2 * 14;
                size_t vrow = (size_t)((bb * 25 + wh * 5 + ww2) * 12) * 64;
                int key = ii * 14 + jj;
                #pragma unroll
                for (int ni = 0; ni < 4; ni++) {
                    int gn = tn + wn + ni * 16 + cl;
                    float v = acc[mi][ni][r] + bv[ni];
                    if (gn < 1536) {
                        outb[(size_t)gm * 2304 + gn] = f2b(v);
                    } else {
                        int hv = gn - 1536;
                        vtg[(vrow + ((hv >> 6) * 64 + (hv & 63))) * 224 + key] = f2b(v);
                    }
                }
            } else if (EPI == 1) {
                #pragma unroll
                for (int ni = 0; ni < 4; ni++) {
                    int gn = tn + wn + ni * 16 + cl;
                    outf[(size_t)gm * 768 + gn] =
                        xres[(size_t)gm * 768 + gn] + acc[mi][ni][r] + bv[ni];
                }
            } else if (EPI == 2) {
                #pragma unroll
                for (int ni = 0; ni < 4; ni++) {
                    int gn = tn + wn + ni * 16 + cl;
                    float v = acc[mi][ni][r] + bv[ni];
                    outb[(size_t)gm * N + gn] =
                        f2b(0.5f * v * (1.0f + erff(v * 0.70710678118654752f)));
                }
            } else {
                #pragma unroll
                for (int ni = 0; ni < 4; ni++) {
                    int gn = tn + wn + ni * 16 + cl;
                    outf[(size_t)gm * 768 + gn] =
                        yres[(size_t)gm * 768 + gn] + acc[mi][ni][r] + bv[ni];
                }
            }
        }
    }
}

// ---------------------------------------------------------------------------
// K3: fused MFMA windowed attention, v3 — NO K/V/table LDS staging.
// B-fragments read straight from global in MFMA operand layout (lane cl =
// output column; garbage in padded lanes only affects discarded columns).
// Per-lane K row pointers (window gather + bias fallback) in a small LDS
// table. vt is 224-key padded (finite), rel tables prebuilt bf16 32x64.
// LDS = 14.5 KB -> ~3 blocks/CU.
// ---------------------------------------------------------------------------
__launch_bounds__(256)
__global__ void attn_kernel(const bf16* __restrict__ qkvb,
                            const bf16* __restrict__ vt,
                            const bf16* __restrict__ bias_bf,
                            const bf16* __restrict__ rhb,
                            const bf16* __restrict__ rwb,
                            bf16* __restrict__ att)
{
    __shared__ unsigned long long ptrs[13][16];
    __shared__ bf16 Ps[4][16 * 36];
    __shared__ bf16 relS[4][2][16 * 32];

    int bh = blockIdx.x;
    int bwi = bh / 12, head = bh % 12;
    int tid = threadIdx.x, w = tid >> 6, lane = tid & 63;
    int b = bwi / 25, wq = bwi % 25;
    int r0 = (wq / 5) * 14, c0 = (wq % 5) * 14;

    // per-lane K row pointers (mt-independent)
    for (int idx = tid; idx < 208; idx += 256) {
        int ni = idx >> 4, c2 = idx & 15;
        int key = ni * 16 + c2;
        int i = key / 14, j = key - i * 14;
        int rr = r0 + i, cc = c0 + j;
        bool valid = (key < 196) && (rr < 64) && (cc < 64);
        const bf16* p = valid
            ? qkvb + ((size_t)((b << 12) + rr * 64 + cc) * 2304 + 768 + head * 64)
            : bias_bf + 768 + head * 64;
        ptrs[ni][c2] = (unsigned long long)p;
    }
    __syncthreads();

    const int cl = lane & 15, rg = lane >> 4;
    const int lr0 = rg * 4;
    const bf16* vbase = vt + (size_t)(bwi * 12 + head) * 64 * 224;

    for (int mt = w; mt < 13; mt += 4) {
        int q0 = mt * 16 + cl;
        int qi = q0 / 14, qj = q0 - qi * 14;
        int qr = r0 + qi, qc = c0 + qj;
        bool qv = (q0 < 196) && (qr < 64) && (qc < 64);
        const bf16* qp = qv
            ? qkvb + ((size_t)((b << 12) + qr * 64 + qc) * 2304 + head * 64)
            : bias_bf + head * 64;
        short8 af0 = *(const short8*)(qp + rg * 8);
        short8 af1 = *(const short8*)(qp + 32 + rg * 8);

        f32x4 sc[17];
        #pragma unroll
        for (int ni = 0; ni < 13; ni++) {
            const bf16* kp = (const bf16*)ptrs[ni][cl];
            short8 blo = *(const short8*)(kp + rg * 8);
            short8 bhi = *(const short8*)(kp + 32 + rg * 8);
            f32x4 t = {};
            t = __builtin_amdgcn_mfma_f32_16x16x32_bf16(af0, blo, t, 0, 0, 0);
            sc[ni] = __builtin_amdgcn_mfma_f32_16x16x32_bf16(af1, bhi, t, 0, 0, 0);
        }
        #pragma unroll
        for (int t2 = 0; t2 < 2; t2++) {
            const bf16* hp = rhb + (t2 * 16 + cl) * 64;
            f32x4 th = {};
            th = __builtin_amdgcn_mfma_f32_16x16x32_bf16(
                af0, *(const short8*)(hp + rg * 8), th, 0, 0, 0);
            sc[13 + t2] = __builtin_amdgcn_mfma_f32_16x16x32_bf16(
                af1, *(const short8*)(hp + 32 + rg * 8), th, 0, 0, 0);
            const bf16* wp2 = rwb + (t2 * 16 + cl) * 64;
            f32x4 tw = {};
            tw = __builtin_amdgcn_mfma_f32_16x16x32_bf16(
                af0, *(const short8*)(wp2 + rg * 8), tw, 0, 0, 0);
            sc[15 + t2] = __builtin_amdgcn_mfma_f32_16x16x32_bf16(
                af1, *(const short8*)(wp2 + 32 + rg * 8), tw, 0, 0, 0);
        }
        // rel tiles -> LDS (cross-lane diagonal gather)
        #pragma unroll
        for (int t2 = 0; t2 < 2; t2++)
            #pragma unroll
            for (int r = 0; r < 4; r++) {
                relS[w][0][(lr0 + r) * 32 + t2 * 16 + cl] = f2b(sc[13 + t2][r]);
                relS[w][1][(lr0 + r) * 32 + t2 * 16 + cl] = f2b(sc[15 + t2][r]);
            }
        __builtin_amdgcn_wave_barrier();

        int iq[4], jq[4];
        #pragma unroll
        for (int r = 0; r < 4; r++) { int q = mt * 16 + lr0 + r; iq[r] = q / 14; jq[r] = q % 14; }
        float mx[4] = { -1e30f, -1e30f, -1e30f, -1e30f };
        #pragma unroll
        for (int ni = 0; ni < 13; ni++) {
            int c = ni * 16 + cl;
            int kh = c / 14; if (kh > 13) kh = 13;
            int kw = c - (c / 14) * 14;
            bool valid = c < 196;
            #pragma unroll
            for (int r = 0; r < 4; r++) {
                float lg = sc[ni][r] * 0.125f
                         + b2f(relS[w][0][(lr0 + r) * 32 + iq[r] - kh + 13])
                         + b2f(relS[w][1][(lr0 + r) * 32 + jq[r] - kw + 13]);
                sc[ni][r] = valid ? lg : -1e30f;
                mx[r] = fmaxf(mx[r], sc[ni][r]);
            }
        }
        float sum[4];
        #pragma unroll
        for (int r = 0; r < 4; r++) {
            #pragma unroll
            for (int o = 1; o < 16; o <<= 1) mx[r] = fmaxf(mx[r], __shfl_xor(mx[r], o));
            sum[r] = 0.f;
        }
        #pragma unroll
        for (int ni = 0; ni < 13; ni++)
            #pragma unroll
            for (int r = 0; r < 4; r++) {
                float e = __expf(sc[ni][r] - mx[r]);
                sc[ni][r] = e; sum[r] += e;
            }
        #pragma unroll
        for (int r = 0; r < 4; r++) {
            #pragma unroll
            for (int o = 1; o < 16; o <<= 1) sum[r] += __shfl_xor(sum[r], o);
            sum[r] = 1.0f / sum[r];
        }
        __builtin_amdgcn_wave_barrier();

        // PV: P slices via per-wave LDS; V frags straight from padded vt
        f32x4 ov[4] = {};
        #pragma unroll
        for (int ks = 0; ks < 7; ks++) {
            #pragma unroll
            for (int r = 0; r < 4; r++) {
                Ps[w][(lr0 + r) * 36 + cl] = f2b(sc[2 * ks][r] * sum[r]);
                Ps[w][(lr0 + r) * 36 + 16 + cl] =
                    (2 * ks + 1 < 13) ? f2b(sc[2 * ks + 1][r] * sum[r]) : f2b(0.0f);
            }
            __builtin_amdgcn_wave_barrier();
            short8 pa = *(const short8*)(&Ps[w][cl * 36 + rg * 8]);
            #pragma unroll
            for (int ni = 0; ni < 4; ni++) {
                short8 vb = *(const short8*)(vbase + (size_t)(ni * 16 + cl) * 224 + ks * 32 + rg * 8);
                ov[ni] = __builtin_amdgcn_mfma_f32_16x16x32_bf16(pa, vb, ov[ni], 0, 0, 0);
            }
            __builtin_amdgcn_wave_barrier();
        }

        #pragma unroll
        for (int r = 0; r < 4; r++) {
            int q = mt * 16 + lr0 + r;
            int i = q / 14, j = q % 14;
            int rr = r0 + i, cc = c0 + j;
            if (q < 196 && rr < 64 && cc < 64) {
                size_t ob = (size_t)((b << 12) + rr * 64 + cc) * 768 + head * 64;
                #pragma unroll
                for (int ni = 0; ni < 4; ni++)
                    att[ob + ni * 16 + cl] = f2b(ov[ni][r]);
            }
        }
    }
}

// ---------------------------------------------------------------------------
// Workspace (MiB offsets, peak ~107 MiB; round-2 proved >=117 usable):
//   0 qkv_wt | 3.5 proj_wt | 5 fc1_wt | 10 fc2_wt
//   14.5 bias_bf (4.6K) | 14.75 rhb (4K) | 14.75+4K rwb (4K)
//   15 xn1/att/xn2 (12.6M) | 28 qkvb 8192x2304 bf16 (37.7M, ends exactly 64M)
//   28 h 8192x3072 bf16 (50.3M, after vt dead) | 64 vt 600x64x224 bf16 (17.2M)
//   82 y 8192x768 f32 (25.2M)
// ---------------------------------------------------------------------------
extern "C" void kernel_launch(void* const* d_in, const int* in_sizes, int n_in,
                              void* d_out, int out_size, void* d_ws, size_t ws_size,
                              hipStream_t stream)
{
    const float* x      = (const float*)d_in[0];
    const float* n1w    = (const float*)d_in[1];
    const float* n1b    = (const float*)d_in[2];
    const float* qkv_w  = (const float*)d_in[3];
    const float* qkv_b  = (const float*)d_in[4];
    const float* proj_w = (const float*)d_in[5];
    const float* proj_b = (const float*)d_in[6];
    const float* rph    = (const float*)d_in[7];
    const float* rpw    = (const float*)d_in[8];
    const float* n2w    = (const float*)d_in[9];
    const float* n2b    = (const float*)d_in[10];
    const float* fc1_w  = (const float*)d_in[11];
    const float* fc1_b  = (const float*)d_in[12];
    const float* fc2_w  = (const float*)d_in[13];
    const float* fc2_b  = (const float*)d_in[14];
    float* out = (float*)d_out;

    char* ws = (char*)d_ws;
    const size_t MB = (size_t)1 << 20;
    bf16* qkv_wt  = (bf16*)(ws);
    bf16* proj_wt = (bf16*)(ws + (size_t)(3.5 * MB));
    bf16* fc1_wt  = (bf16*)(ws + 5 * MB);
    bf16* fc2_wt  = (bf16*)(ws + 10 * MB);
    bf16* bias_bf = (bf16*)(ws + (size_t)(14.5 * MB));
    bf16* rhb     = (bf16*)(ws + (size_t)(14.75 * MB));
    bf16* rwb     = (bf16*)(ws + (size_t)(14.75 * MB) + 4096);
    bf16* xn1     = (bf16*)(ws + 15 * MB);
    bf16* att     = (bf16*)(ws + 15 * MB);
    bf16* xn2     = (bf16*)(ws + 15 * MB);
    bf16* qkvb    = (bf16*)(ws + 28 * MB);
    bf16* h       = (bf16*)(ws + 28 * MB);
    bf16* vt      = (bf16*)(ws + 64 * MB);
    float* y      = (float*)(ws + 82 * MB);

    transpose_all<<<6912, 256, 0, stream>>>(qkv_w, proj_w, fc1_w, fc2_w,
                                            qkv_wt, proj_wt, fc1_wt, fc2_wt);
    fill_kernel<<<601, 256, 0, stream>>>(qkv_b, rph, rpw, vt, bias_bf, rhb, rwb);

    ln_kernel<<<8192, 256, 0, stream>>>(x, n1w, n1b, xn1);
    mfma_gemm<0, 128><<<dim3(18, 64), 256, 0, stream>>>(
        xn1, qkv_wt, qkv_b, qkvb, nullptr, nullptr, nullptr, vt, 8192, 2304, 768);
    attn_kernel<<<600, 256, 0, stream>>>(qkvb, vt, bias_bf, rhb, rwb, att);
    mfma_gemm<1, 64><<<dim3(6, 128), 256, 0, stream>>>(
        att, proj_wt, proj_b, nullptr, y, x, nullptr, nullptr, 8192, 768, 768);
    ln_kernel<<<8192, 256, 0, stream>>>(y, n2w, n2b, xn2);
    mfma_gemm<2, 128><<<dim3(24, 64), 256, 0, stream>>>(
        xn2, fc1_wt, fc1_b, h, nullptr, nullptr, nullptr, nullptr, 8192, 3072, 768);
    mfma_gemm<3, 64><<<dim3(6, 128), 256, 0, stream>>>(
        h, fc2_wt, fc2_b, nullptr, out, nullptr, y, nullptr, 8192, 768, 3072);
}

// Round 9
// 447.218 us; speedup vs baseline: 1.0287x; 1.0287x over previous
//
#include <hip/hip_runtime.h>
#include <hip/hip_bf16.h>
#include <math.h>

typedef __hip_bfloat16 bf16;
typedef __attribute__((ext_vector_type(8))) short short8;
typedef __attribute__((ext_vector_type(4))) float f32x4;

__device__ __forceinline__ float b2f(bf16 v) { return __bfloat162float(v); }
__device__ __forceinline__ bf16 f2b(float f) { return __float2bfloat16(f); }

// ---------------------------------------------------------------------------
// K0: all 4 weight transposes (fp32 KxN -> bf16 NxK) in one launch.
// ---------------------------------------------------------------------------
__launch_bounds__(256)
__global__ void transpose_all(const float* __restrict__ qkv_w,
                              const float* __restrict__ proj_w,
                              const float* __restrict__ fc1_w,
                              const float* __restrict__ fc2_w,
                              bf16* __restrict__ qkv_wt,
                              bf16* __restrict__ proj_wt,
                              bf16* __restrict__ fc1_wt,
                              bf16* __restrict__ fc2_wt)
{
    __shared__ float t[32][33];
    int id = blockIdx.x;
    const float* W; bf16* Wt; int K, N, tix, tiy;
    if (id < 1728)      { W = qkv_w;  Wt = qkv_wt;  K = 768;  N = 2304; tix = id % 72;           tiy = id / 72; }
    else if (id < 2304) { W = proj_w; Wt = proj_wt; K = 768;  N = 768;  tix = (id - 1728) % 24;  tiy = (id - 1728) / 24; }
    else if (id < 4608) { W = fc1_w;  Wt = fc1_wt;  K = 768;  N = 3072; tix = (id - 2304) % 96;  tiy = (id - 2304) / 96; }
    else                { W = fc2_w;  Wt = fc2_wt;  K = 3072; N = 768;  tix = (id - 4608) % 24;  tiy = (id - 4608) / 24; }
    int n0 = tix * 32, k0 = tiy * 32;
    int tx = threadIdx.x & 31, ty = threadIdx.x >> 5;   // 32 x 8
    #pragma unroll
    for (int i = 0; i < 4; i++)
        t[ty * 4 + i][tx] = W[(size_t)(k0 + ty * 4 + i) * N + n0 + tx];
    __syncthreads();
    #pragma unroll
    for (int i = 0; i < 4; i++)
        Wt[(size_t)(n0 + ty * 4 + i) * K + k0 + tx] = f2b(t[tx][ty * 4 + i]);
}

// ---------------------------------------------------------------------------
// K0b: vt pad-fill (keys 196..223 zero everywhere; padded-window keys get
// v_bias); convert qkv_b -> bf16.
// ---------------------------------------------------------------------------
__launch_bounds__(256)
__global__ void fill_kernel(const float* __restrict__ qkv_b,
                            bf16* __restrict__ vt,
                            bf16* __restrict__ bias_bf)
{
    int blk = blockIdx.x;
    int tid = threadIdx.x;
    if (blk == 600) {
        for (int c = tid; c < 2304; c += 256) bias_bf[c] = f2b(qkv_b[c]);
        return;
    }
    int bwi = blk / 12, head = blk % 12;
    size_t base = (size_t)(bwi * 12 + head) * 64 * 224;
    for (int t = tid; t < 64 * 28; t += 256) {
        int d = t / 28, k = 196 + t % 28;
        vt[base + (size_t)d * 224 + k] = f2b(0.0f);
    }
    int wq = bwi % 25;
    int hi = ((wq / 5) == 4) ? 8 : 14;
    int wi = ((wq % 5) == 4) ? 8 : 14;
    if (hi == 14 && wi == 14) return;
    for (int t = tid; t < 196 * 64; t += 256) {
        int d = t & 63, key = t >> 6;
        int i = key / 14, j = key % 14;
        if (i >= hi || j >= wi)
            vt[base + (size_t)d * 224 + key] = f2b(qkv_b[1536 + head * 64 + d]);
    }
}

// ---------------------------------------------------------------------------
// K1/K5: LayerNorm (fp32 in, 768 cols) -> bf16 out.
// ---------------------------------------------------------------------------
__launch_bounds__(256)
__global__ void ln_kernel(const float* __restrict__ y,
                          const float* __restrict__ wgt,
                          const float* __restrict__ bia,
                          bf16* __restrict__ xn)
{
    int blk = blockIdx.x;
    const float* yin = y + (size_t)blk * 768;
    bf16* out = xn + (size_t)blk * 768;
    int tid = threadIdx.x;
    float v[3]; float s = 0.f, ss = 0.f;
    #pragma unroll
    for (int t = 0; t < 3; t++) {
        float f = yin[tid + t * 256];
        v[t] = f; s += f; ss += f * f;
    }
    #pragma unroll
    for (int o = 32; o > 0; o >>= 1) { s += __shfl_xor(s, o); ss += __shfl_xor(ss, o); }
    __shared__ float red[8];
    int w = tid >> 6, lane = tid & 63;
    if (lane == 0) { red[w] = s; red[4 + w] = ss; }
    __syncthreads();
    s  = red[0] + red[1] + red[2] + red[3];
    ss = red[4] + red[5] + red[6] + red[7];
    float mu = s * (1.0f / 768.0f);
    float var = ss * (1.0f / 768.0f) - mu * mu;
    float rs = rsqrtf(var + 1e-5f);
    #pragma unroll
    for (int t = 0; t < 3; t++) {
        int c = tid + t * 256;
        out[c] = f2b((v[t] - mu) * rs * wgt[c] + bia[c]);
    }
}

// ---------------------------------------------------------------------------
// MFMA GEMM: C = A(M x K) @ Bt^T + bias.  BK=64 (two BK=32 LDS buffers),
// XCD-aware swizzle (x-siblings share f%8 -> same XCD L2).  (unchanged)
// ---------------------------------------------------------------------------
template<int EPI, int BM>
__launch_bounds__(256)
__global__ void mfma_gemm(const bf16* __restrict__ A,
                          const bf16* __restrict__ Bt,
                          const float* __restrict__ bias,
                          bf16* __restrict__ outb,
                          float* __restrict__ outf,
                          const float* __restrict__ xres,
                          const float* __restrict__ yres,
                          bf16* __restrict__ vtg,
                          int M, int N, int K)
{
    constexpr int MI = BM / 32;
    __shared__ bf16 As0[BM * 32];
    __shared__ bf16 As1[BM * 32];
    __shared__ bf16 Bs0[128 * 32];
    __shared__ bf16 Bs1[128 * 32];
    const int tid = threadIdx.x;
    const int w = tid >> 6, lane = tid & 63;
    const int cl = lane & 15, rg = lane >> 4;
    const int wm = (w & 1) * (BM / 2), wn = (w >> 1) * 64;

    const int gx = gridDim.x;
    int f = blockIdx.x + gx * blockIdx.y;
    int g = f / (8 * gx), r8 = f % (8 * gx);
    const int tm = (g * 8 + (r8 & 7)) * BM;
    const int tn = (r8 >> 3) * 128;

    f32x4 acc[MI][4] = {};

    for (int k0 = 0; k0 < K; k0 += 64) {
        #pragma unroll
        for (int i = 0; i < BM / 64; i++) {
            int e = i * 256 + tid;
            int r = e >> 2, ch = e & 3;
            const bf16* ap = A + (size_t)(tm + r) * K + k0 + ch * 8;
            __builtin_amdgcn_global_load_lds(
                (const __attribute__((address_space(1))) unsigned*)(ap),
                (__attribute__((address_space(3))) unsigned*)(As0 + e * 8), 16, 0, 0);
            __builtin_amdgcn_global_load_lds(
                (const __attribute__((address_space(1))) unsigned*)(ap + 32),
                (__attribute__((address_space(3))) unsigned*)(As1 + e * 8), 16, 0, 0);
        }
        #pragma unroll
        for (int i = 0; i < 2; i++) {
            int e = i * 256 + tid;
            int r = e >> 2, ch = e & 3;
            const bf16* bp = Bt + (size_t)(tn + r) * K + k0 + ch * 8;
            __builtin_amdgcn_global_load_lds(
                (const __attribute__((address_space(1))) unsigned*)(bp),
                (__attribute__((address_space(3))) unsigned*)(Bs0 + e * 8), 16, 0, 0);
            __builtin_amdgcn_global_load_lds(
                (const __attribute__((address_space(1))) unsigned*)(bp + 32),
                (__attribute__((address_space(3))) unsigned*)(Bs1 + e * 8), 16, 0, 0);
        }
        __syncthreads();
        #pragma unroll
        for (int kk = 0; kk < 2; kk++) {
            const bf16* Ab = kk ? As1 : As0;
            const bf16* Bb = kk ? Bs1 : Bs0;
            short8 af[MI], bfr[4];
            #pragma unroll
            for (int mi = 0; mi < MI; mi++)
                af[mi] = *(const short8*)(Ab + (wm + mi * 16 + cl) * 32 + rg * 8);
            #pragma unroll
            for (int ni = 0; ni < 4; ni++)
                bfr[ni] = *(const short8*)(Bb + (wn + ni * 16 + cl) * 32 + rg * 8);
            #pragma unroll
            for (int mi = 0; mi < MI; mi++)
                #pragma unroll
                for (int ni = 0; ni < 4; ni++)
                    acc[mi][ni] = __builtin_amdgcn_mfma_f32_16x16x32_bf16(
                        af[mi], bfr[ni], acc[mi][ni], 0, 0, 0);
        }
        __syncthreads();
    }

    const int row_l = rg * 4;
    float bv[4];
    #pragma unroll
    for (int ni = 0; ni < 4; ni++) bv[ni] = bias[tn + wn + ni * 16 + cl];

    #pragma unroll
    for (int mi = 0; mi < MI; mi++) {
        #pragma unroll
        for (int r = 0; r < 4; r++) {
            int gm = tm + wm + mi * 16 + row_l + r;
            if (EPI == 0) {
                int bb = gm >> 12, rr = (gm >> 6) & 63, cc = gm & 63;
                int wh = rr / 14, ii = rr - wh * 14;
                int ww2 = cc / 14, jj = cc - ww2 * 14;
                size_t vrow = (size_t)((bb * 25 + wh * 5 + ww2) * 12) * 64;
                int key = ii * 14 + jj;
                #pragma unroll
                for (int ni = 0; ni < 4; ni++) {
                    int gn = tn + wn + ni * 16 + cl;
                    float v = acc[mi][ni][r] + bv[ni];
                    if (gn < 1536) {
                        outb[(size_t)gm * 2304 + gn] = f2b(v);
                    } else {
                        int hv = gn - 1536;
                        vtg[(vrow + ((hv >> 6) * 64 + (hv & 63))) * 224 + key] = f2b(v);
                    }
                }
            } else if (EPI == 1) {
                #pragma unroll
                for (int ni = 0; ni < 4; ni++) {
                    int gn = tn + wn + ni * 16 + cl;
                    outf[(size_t)gm * 768 + gn] =
                        xres[(size_t)gm * 768 + gn] + acc[mi][ni][r] + bv[ni];
                }
            } else if (EPI == 2) {
                #pragma unroll
                for (int ni = 0; ni < 4; ni++) {
                    int gn = tn + wn + ni * 16 + cl;
                    float v = acc[mi][ni][r] + bv[ni];
                    outb[(size_t)gm * N + gn] =
                        f2b(0.5f * v * (1.0f + erff(v * 0.70710678118654752f)));
                }
            } else {
                #pragma unroll
                for (int ni = 0; ni < 4; ni++) {
                    int gn = tn + wn + ni * 16 + cl;
                    outf[(size_t)gm * 768 + gn] =
                        yres[(size_t)gm * 768 + gn] + acc[mi][ni][r] + bv[ni];
                }
            }
        }
    }
}

// ---------------------------------------------------------------------------
// K3: fused MFMA windowed attention, v4 = round-7 structure (K + rel tables
// staged in LDS — proven fast) + round-8 V path (PV B-frags direct from the
// 224-stride padded vt: affine per-lane address, no pointer table).
// LDS 47.6 KB; no Vt buffer, no V staging traffic.
// ---------------------------------------------------------------------------
__launch_bounds__(256)
__global__ void attn_kernel(const bf16* __restrict__ qkv,
                            const bf16* __restrict__ vt,
                            const bf16* __restrict__ bias_bf,
                            const float* __restrict__ rel_h,
                            const float* __restrict__ rel_w,
                            bf16* __restrict__ att)
{
    __shared__ bf16 BsLo[272 * 32];
    __shared__ bf16 BsHi[272 * 32];
    __shared__ bf16 Ps[4][16 * 36];
    __shared__ bf16 relS[4][2][16 * 32];

    int bh = blockIdx.x;
    int bwi = bh / 12, head = bh % 12;
    int tid = threadIdx.x, w = tid >> 6, lane = tid & 63;
    int b = bwi / 25, wq = bwi % 25;
    int r0 = (wq / 5) * 14, c0 = (wq % 5) * 14;

    for (int idx = tid; idx < 76 * 16; idx += 256) {
        int r = 196 + (idx >> 4), cd = idx & 15;
        ((unsigned*)BsLo)[r * 16 + cd] = 0u;
        ((unsigned*)BsHi)[r * 16 + cd] = 0u;
    }
    for (int idx = tid; idx < 196 * 32; idx += 256) {
        int m = idx >> 5, c2 = idx & 31;
        int i = m / 14, j = m % 14;
        int rr = r0 + i, cc = c0 + j;
        const bf16* src = (rr < 64 && cc < 64)
            ? qkv + ((size_t)((b << 12) + rr * 64 + cc) * 2304 + 768 + head * 64)
            : bias_bf + 768 + head * 64;
        unsigned u = *(const unsigned*)(src + 2 * c2);
        if (c2 < 16) ((unsigned*)BsLo)[m * 16 + c2] = u;
        else         ((unsigned*)BsHi)[m * 16 + (c2 - 16)] = u;
    }
    for (int idx = tid; idx < 27 * 32; idx += 256) {
        int t = idx >> 5, c2 = idx & 31;
        float2 h2 = *(const float2*)(rel_h + t * 64 + 2 * c2);
        float2 w2 = *(const float2*)(rel_w + t * 64 + 2 * c2);
        bf16 hb[2] = { f2b(h2.x), f2b(h2.y) };
        bf16 wb[2] = { f2b(w2.x), f2b(w2.y) };
        int r1 = 208 + t, r2 = 240 + t;
        if (c2 < 16) {
            ((unsigned*)BsLo)[r1 * 16 + c2] = *(unsigned*)hb;
            ((unsigned*)BsLo)[r2 * 16 + c2] = *(unsigned*)wb;
        } else {
            ((unsigned*)BsHi)[r1 * 16 + c2 - 16] = *(unsigned*)hb;
            ((unsigned*)BsHi)[r2 * 16 + c2 - 16] = *(unsigned*)wb;
        }
    }
    __syncthreads();

    const int cl = lane & 15, rg = lane >> 4;
    const int lr0 = rg * 4;
    const bf16* vbase = vt + (size_t)(bwi * 12 + head) * 64 * 224;

    for (int mt = w; mt < 13; mt += 4) {
        int q0 = mt * 16 + cl;
        int qi = q0 / 14, qj = q0 % 14;
        int qr = r0 + qi, qc = c0 + qj;
        bool qv = (q0 < 196) && (qr < 64) && (qc < 64);
        const bf16* qp = qv
            ? qkv + ((size_t)((b << 12) + qr * 64 + qc) * 2304 + head * 64 + rg * 8)
            : bias_bf + head * 64 + rg * 8;
        short8 af0 = *(const short8*)(qp);
        short8 af1 = *(const short8*)(qp + 32);

        f32x4 sc[17];
        #pragma unroll
        for (int ni = 0; ni < 17; ni++) {
            short8 blo = *(const short8*)(BsLo + (ni * 16 + cl) * 32 + rg * 8);
            short8 bhi = *(const short8*)(BsHi + (ni * 16 + cl) * 32 + rg * 8);
            f32x4 t = {};
            t = __builtin_amdgcn_mfma_f32_16x16x32_bf16(af0, blo, t, 0, 0, 0);
            sc[ni] = __builtin_amdgcn_mfma_f32_16x16x32_bf16(af1, bhi, t, 0, 0, 0);
        }
        #pragma unroll
        for (int t2 = 0; t2 < 2; t2++)
            #pragma unroll
            for (int r = 0; r < 4; r++) {
                relS[w][0][(lr0 + r) * 32 + t2 * 16 + cl] = f2b(sc[13 + t2][r]);
                relS[w][1][(lr0 + r) * 32 + t2 * 16 + cl] = f2b(sc[15 + t2][r]);
            }
        __builtin_amdgcn_wave_barrier();

        int iq[4], jq[4];
        #pragma unroll
        for (int r = 0; r < 4; r++) { int q = mt * 16 + lr0 + r; iq[r] = q / 14; jq[r] = q % 14; }
        float mx[4] = { -1e30f, -1e30f, -1e30f, -1e30f };
        #pragma unroll
        for (int ni = 0; ni < 13; ni++) {
            int c = ni * 16 + cl;
            int kh = c / 14; if (kh > 13) kh = 13;
            int kw = c - (c / 14) * 14;
            bool valid = c < 196;
            #pragma unroll
            for (int r = 0; r < 4; r++) {
                float lg = sc[ni][r] * 0.125f
                         + b2f(relS[w][0][(lr0 + r) * 32 + iq[r] - kh + 13])
                         + b2f(relS[w][1][(lr0 + r) * 32 + jq[r] - kw + 13]);
                sc[ni][r] = valid ? lg : -1e30f;
                mx[r] = fmaxf(mx[r], sc[ni][r]);
            }
        }
        float sum[4];
        #pragma unroll
        for (int r = 0; r < 4; r++) {
            #pragma unroll
            for (int o = 1; o < 16; o <<= 1) mx[r] = fmaxf(mx[r], __shfl_xor(mx[r], o));
            sum[r] = 0.f;
        }
        #pragma unroll
        for (int ni = 0; ni < 13; ni++)
            #pragma unroll
            for (int r = 0; r < 4; r++) {
                float e = __expf(sc[ni][r] - mx[r]);
                sc[ni][r] = e; sum[r] += e;
            }
        #pragma unroll
        for (int r = 0; r < 4; r++) {
            #pragma unroll
            for (int o = 1; o < 16; o <<= 1) sum[r] += __shfl_xor(sum[r], o);
            sum[r] = 1.0f / sum[r];
        }

        f32x4 ov[4] = {};
        #pragma unroll
        for (int ks = 0; ks < 7; ks++) {
            #pragma unroll
            for (int r = 0; r < 4; r++) {
                Ps[w][(lr0 + r) * 36 + cl] = f2b(sc[2 * ks][r] * sum[r]);
                Ps[w][(lr0 + r) * 36 + 16 + cl] =
                    (2 * ks + 1 < 13) ? f2b(sc[2 * ks + 1][r] * sum[r]) : f2b(0.0f);
            }
            __builtin_amdgcn_wave_barrier();
            short8 pa = *(const short8*)(&Ps[w][cl * 36 + rg * 8]);
            #pragma unroll
            for (int ni = 0; ni < 4; ni++) {
                short8 vb = *(const short8*)(vbase + (size_t)(ni * 16 + cl) * 224 + ks * 32 + rg * 8);
                ov[ni] = __builtin_amdgcn_mfma_f32_16x16x32_bf16(pa, vb, ov[ni], 0, 0, 0);
            }
            __builtin_amdgcn_wave_barrier();
        }

        #pragma unroll
        for (int r = 0; r < 4; r++) {
            int q = mt * 16 + lr0 + r;
            int i = q / 14, j = q % 14;
            int rr = r0 + i, cc = c0 + j;
            if (q < 196 && rr < 64 && cc < 64) {
                size_t ob = (size_t)((b << 12) + rr * 64 + cc) * 768 + head * 64;
                #pragma unroll
                for (int ni = 0; ni < 4; ni++)
                    att[ob + ni * 16 + cl] = f2b(ov[ni][r]);
            }
        }
    }
}

// ---------------------------------------------------------------------------
// Workspace (MiB offsets, peak ~107 MiB):
//   0 qkv_wt | 3.5 proj_wt | 5 fc1_wt | 10 fc2_wt | 14.5 bias_bf
//   15 xn1/att/xn2 | 28 qkvb (37.7M) / later h (50.3M)
//   64 vt 50x12x64x224 bf16 (17.2M) | 82 y 8192x768 f32
// ---------------------------------------------------------------------------
extern "C" void kernel_launch(void* const* d_in, const int* in_sizes, int n_in,
                              void* d_out, int out_size, void* d_ws, size_t ws_size,
                              hipStream_t stream)
{
    const float* x      = (const float*)d_in[0];
    const float* n1w    = (const float*)d_in[1];
    const float* n1b    = (const float*)d_in[2];
    const float* qkv_w  = (const float*)d_in[3];
    const float* qkv_b  = (const float*)d_in[4];
    const float* proj_w = (const float*)d_in[5];
    const float* proj_b = (const float*)d_in[6];
    const float* rph    = (const float*)d_in[7];
    const float* rpw    = (const float*)d_in[8];
    const float* n2w    = (const float*)d_in[9];
    const float* n2b    = (const float*)d_in[10];
    const float* fc1_w  = (const float*)d_in[11];
    const float* fc1_b  = (const float*)d_in[12];
    const float* fc2_w  = (const float*)d_in[13];
    const float* fc2_b  = (const float*)d_in[14];
    float* out = (float*)d_out;

    char* ws = (char*)d_ws;
    const size_t MB = (size_t)1 << 20;
    bf16* qkv_wt  = (bf16*)(ws);
    bf16* proj_wt = (bf16*)(ws + (size_t)(3.5 * MB));
    bf16* fc1_wt  = (bf16*)(ws + 5 * MB);
    bf16* fc2_wt  = (bf16*)(ws + 10 * MB);
    bf16* bias_bf = (bf16*)(ws + (size_t)(14.5 * MB));
    bf16* xn1     = (bf16*)(ws + 15 * MB);
    bf16* att     = (bf16*)(ws + 15 * MB);
    bf16* xn2     = (bf16*)(ws + 15 * MB);
    bf16* qkvb    = (bf16*)(ws + 28 * MB);
    bf16* h       = (bf16*)(ws + 28 * MB);
    bf16* vt      = (bf16*)(ws + 64 * MB);
    float* y      = (float*)(ws + 82 * MB);

    transpose_all<<<6912, 256, 0, stream>>>(qkv_w, proj_w, fc1_w, fc2_w,
                                            qkv_wt, proj_wt, fc1_wt, fc2_wt);
    fill_kernel<<<601, 256, 0, stream>>>(qkv_b, vt, bias_bf);

    ln_kernel<<<8192, 256, 0, stream>>>(x, n1w, n1b, xn1);
    mfma_gemm<0, 128><<<dim3(18, 64), 256, 0, stream>>>(
        xn1, qkv_wt, qkv_b, qkvb, nullptr, nullptr, nullptr, vt, 8192, 2304, 768);
    attn_kernel<<<600, 256, 0, stream>>>(qkvb, vt, bias_bf, rph, rpw, att);
    mfma_gemm<1, 64><<<dim3(6, 128), 256, 0, stream>>>(
        att, proj_wt, proj_b, nullptr, y, x, nullptr, nullptr, 8192, 768, 768);
    ln_kernel<<<8192, 256, 0, stream>>>(y, n2w, n2b, xn2);
    mfma_gemm<2, 128><<<dim3(24, 64), 256, 0, stream>>>(
        xn2, fc1_wt, fc1_b, h, nullptr, nullptr, nullptr, nullptr, 8192, 3072, 768);
    mfma_gemm<3, 64><<<dim3(6, 128), 256, 0, stream>>>(
        h, fc2_wt, fc2_b, nullptr, out, nullptr, y, nullptr, 8192, 768, 3072);
}

// Round 10
// 420.927 us; speedup vs baseline: 1.0930x; 1.0625x over previous
//
#include <hip/hip_runtime.h>
#include <hip/hip_bf16.h>
#include <math.h>

typedef __hip_bfloat16 bf16;
typedef __attribute__((ext_vector_type(8))) short short8;
typedef __attribute__((ext_vector_type(4))) float f32x4;

__device__ __forceinline__ float b2f(bf16 v) { return __bfloat162float(v); }
__device__ __forceinline__ bf16 f2b(float f) { return __float2bfloat16(f); }

// ---------------------------------------------------------------------------
// K0: all 4 weight transposes (fp32 KxN -> bf16 NxK) in one launch.
// ---------------------------------------------------------------------------
__launch_bounds__(256)
__global__ void transpose_all(const float* __restrict__ qkv_w,
                              const float* __restrict__ proj_w,
                              const float* __restrict__ fc1_w,
                              const float* __restrict__ fc2_w,
                              bf16* __restrict__ qkv_wt,
                              bf16* __restrict__ proj_wt,
                              bf16* __restrict__ fc1_wt,
                              bf16* __restrict__ fc2_wt)
{
    __shared__ float t[32][33];
    int id = blockIdx.x;
    const float* W; bf16* Wt; int K, N, tix, tiy;
    if (id < 1728)      { W = qkv_w;  Wt = qkv_wt;  K = 768;  N = 2304; tix = id % 72;           tiy = id / 72; }
    else if (id < 2304) { W = proj_w; Wt = proj_wt; K = 768;  N = 768;  tix = (id - 1728) % 24;  tiy = (id - 1728) / 24; }
    else if (id < 4608) { W = fc1_w;  Wt = fc1_wt;  K = 768;  N = 3072; tix = (id - 2304) % 96;  tiy = (id - 2304) / 96; }
    else                { W = fc2_w;  Wt = fc2_wt;  K = 3072; N = 768;  tix = (id - 4608) % 24;  tiy = (id - 4608) / 24; }
    int n0 = tix * 32, k0 = tiy * 32;
    int tx = threadIdx.x & 31, ty = threadIdx.x >> 5;   // 32 x 8
    #pragma unroll
    for (int i = 0; i < 4; i++)
        t[ty * 4 + i][tx] = W[(size_t)(k0 + ty * 4 + i) * N + n0 + tx];
    __syncthreads();
    #pragma unroll
    for (int i = 0; i < 4; i++)
        Wt[(size_t)(n0 + ty * 4 + i) * K + k0 + tx] = f2b(t[tx][ty * 4 + i]);
}

// ---------------------------------------------------------------------------
// K0b: fill vt padded-window keys with v_bias; convert qkv_b -> bf16;
// build bf16 rel tables (32 x 64, rows >= 27 zero).
// ---------------------------------------------------------------------------
__launch_bounds__(256)
__global__ void fill_kernel(const float* __restrict__ qkv_b,
                            const float* __restrict__ rel_h,
                            const float* __restrict__ rel_w,
                            bf16* __restrict__ vt,
                            bf16* __restrict__ bias_bf,
                            bf16* __restrict__ rhb,
                            bf16* __restrict__ rwb)
{
    int blk = blockIdx.x;
    int tid = threadIdx.x;
    if (blk == 600) {
        for (int c = tid; c < 2304; c += 256) bias_bf[c] = f2b(qkv_b[c]);
        for (int idx = tid; idx < 2048; idx += 256) {
            int r = idx >> 6, c = idx & 63;
            rhb[idx] = (r < 27) ? f2b(rel_h[r * 64 + c]) : f2b(0.0f);
            rwb[idx] = (r < 27) ? f2b(rel_w[r * 64 + c]) : f2b(0.0f);
        }
        return;
    }
    int bwi = blk / 12, head = blk % 12;
    int wq = bwi % 25;
    int hi = ((wq / 5) == 4) ? 8 : 14;
    int wi = ((wq % 5) == 4) ? 8 : 14;
    if (hi == 14 && wi == 14) return;
    size_t base = (size_t)(bwi * 12 + head) * 64 * 196;
    for (int t = tid; t < 196 * 64; t += 256) {
        int d = t & 63, key = t >> 6;
        int i = key / 14, j = key % 14;
        if (i >= hi || j >= wi)
            vt[base + (size_t)d * 196 + key] = f2b(qkv_b[1536 + head * 64 + d]);
    }
}

// ---------------------------------------------------------------------------
// K1/K5: LayerNorm (fp32 in, 768 cols) -> bf16 out.
// ---------------------------------------------------------------------------
__launch_bounds__(256)
__global__ void ln_kernel(const float* __restrict__ y,
                          const float* __restrict__ wgt,
                          const float* __restrict__ bia,
                          bf16* __restrict__ xn)
{
    int blk = blockIdx.x;
    const float* yin = y + (size_t)blk * 768;
    bf16* out = xn + (size_t)blk * 768;
    int tid = threadIdx.x;
    float v[3]; float s = 0.f, ss = 0.f;
    #pragma unroll
    for (int t = 0; t < 3; t++) {
        float f = yin[tid + t * 256];
        v[t] = f; s += f; ss += f * f;
    }
    #pragma unroll
    for (int o = 32; o > 0; o >>= 1) { s += __shfl_xor(s, o); ss += __shfl_xor(ss, o); }
    __shared__ float red[8];
    int w = tid >> 6, lane = tid & 63;
    if (lane == 0) { red[w] = s; red[4 + w] = ss; }
    __syncthreads();
    s  = red[0] + red[1] + red[2] + red[3];
    ss = red[4] + red[5] + red[6] + red[7];
    float mu = s * (1.0f / 768.0f);
    float var = ss * (1.0f / 768.0f) - mu * mu;
    float rs = rsqrtf(var + 1e-5f);
    #pragma unroll
    for (int t = 0; t < 3; t++) {
        int c = tid + t * 256;
        out[c] = f2b((v[t] - mu) * rs * wgt[c] + bia[c]);
    }
}

// ---------------------------------------------------------------------------
// MFMA GEMM: C = A(M x K) @ Bt^T + bias.  BK=64 (two BK=32 LDS buffers),
// XCD-aware swizzle (x-siblings share f%8 -> same XCD L2).  (unchanged)
// ---------------------------------------------------------------------------
template<int EPI, int BM>
__launch_bounds__(256)
__global__ void mfma_gemm(const bf16* __restrict__ A,
                          const bf16* __restrict__ Bt,
                          const float* __restrict__ bias,
                          bf16* __restrict__ outb,
                          float* __restrict__ outf,
                          const float* __restrict__ xres,
                          const float* __restrict__ yres,
                          bf16* __restrict__ vtg,
                          int M, int N, int K)
{
    constexpr int MI = BM / 32;
    __shared__ bf16 As0[BM * 32];
    __shared__ bf16 As1[BM * 32];
    __shared__ bf16 Bs0[128 * 32];
    __shared__ bf16 Bs1[128 * 32];
    const int tid = threadIdx.x;
    const int w = tid >> 6, lane = tid & 63;
    const int cl = lane & 15, rg = lane >> 4;
    const int wm = (w & 1) * (BM / 2), wn = (w >> 1) * 64;

    const int gx = gridDim.x;
    int f = blockIdx.x + gx * blockIdx.y;
    int g = f / (8 * gx), r8 = f % (8 * gx);
    const int tm = (g * 8 + (r8 & 7)) * BM;
    const int tn = (r8 >> 3) * 128;

    f32x4 acc[MI][4] = {};

    for (int k0 = 0; k0 < K; k0 += 64) {
        #pragma unroll
        for (int i = 0; i < BM / 64; i++) {
            int e = i * 256 + tid;
            int r = e >> 2, ch = e & 3;
            const bf16* ap = A + (size_t)(tm + r) * K + k0 + ch * 8;
            __builtin_amdgcn_global_load_lds(
                (const __attribute__((address_space(1))) unsigned*)(ap),
                (__attribute__((address_space(3))) unsigned*)(As0 + e * 8), 16, 0, 0);
            __builtin_amdgcn_global_load_lds(
                (const __attribute__((address_space(1))) unsigned*)(ap + 32),
                (__attribute__((address_space(3))) unsigned*)(As1 + e * 8), 16, 0, 0);
        }
        #pragma unroll
        for (int i = 0; i < 2; i++) {
            int e = i * 256 + tid;
            int r = e >> 2, ch = e & 3;
            const bf16* bp = Bt + (size_t)(tn + r) * K + k0 + ch * 8;
            __builtin_amdgcn_global_load_lds(
                (const __attribute__((address_space(1))) unsigned*)(bp),
                (__attribute__((address_space(3))) unsigned*)(Bs0 + e * 8), 16, 0, 0);
            __builtin_amdgcn_global_load_lds(
                (const __attribute__((address_space(1))) unsigned*)(bp + 32),
                (__attribute__((address_space(3))) unsigned*)(Bs1 + e * 8), 16, 0, 0);
        }
        __syncthreads();
        #pragma unroll
        for (int kk = 0; kk < 2; kk++) {
            const bf16* Ab = kk ? As1 : As0;
            const bf16* Bb = kk ? Bs1 : Bs0;
            short8 af[MI], bfr[4];
            #pragma unroll
            for (int mi = 0; mi < MI; mi++)
                af[mi] = *(const short8*)(Ab + (wm + mi * 16 + cl) * 32 + rg * 8);
            #pragma unroll
            for (int ni = 0; ni < 4; ni++)
                bfr[ni] = *(const short8*)(Bb + (wn + ni * 16 + cl) * 32 + rg * 8);
            #pragma unroll
            for (int mi = 0; mi < MI; mi++)
                #pragma unroll
                for (int ni = 0; ni < 4; ni++)
                    acc[mi][ni] = __builtin_amdgcn_mfma_f32_16x16x32_bf16(
                        af[mi], bfr[ni], acc[mi][ni], 0, 0, 0);
        }
        __syncthreads();
    }

    const int row_l = rg * 4;
    float bv[4];
    #pragma unroll
    for (int ni = 0; ni < 4; ni++) bv[ni] = bias[tn + wn + ni * 16 + cl];

    #pragma unroll
    for (int mi = 0; mi < MI; mi++) {
        #pragma unroll
        for (int r = 0; r < 4; r++) {
            int gm = tm + wm + mi * 16 + row_l + r;
            if (EPI == 0) {
                int bb = gm >> 12, rr = (gm >> 6) & 63, cc = gm & 63;
                int wh = rr / 14, ii = rr - wh * 14;
                int ww2 = cc / 14, jj = cc - ww2 * 14;
                size_t vrow = (size_t)((bb * 25 + wh * 5 + ww2) * 12) * 64;
                int key = ii * 14 + jj;
                #pragma unroll
                for (int ni = 0; ni < 4; ni++) {
                    int gn = tn + wn + ni * 16 + cl;
                    float v = acc[mi][ni][r] + bv[ni];
                    if (gn < 1536) {
                        outb[(size_t)gm * 2304 + gn] = f2b(v);
                    } else {
                        int hv = gn - 1536;
                        vtg[(vrow + ((hv >> 6) * 64 + (hv & 63))) * 196 + key] = f2b(v);
                    }
                }
            } else if (EPI == 1) {
                #pragma unroll
                for (int ni = 0; ni < 4; ni++) {
                    int gn = tn + wn + ni * 16 + cl;
                    outf[(size_t)gm * 768 + gn] =
                        xres[(size_t)gm * 768 + gn] + acc[mi][ni][r] + bv[ni];
                }
            } else if (EPI == 2) {
                #pragma unroll
                for (int ni = 0; ni < 4; ni++) {
                    int gn = tn + wn + ni * 16 + cl;
                    float v = acc[mi][ni][r] + bv[ni];
                    outb[(size_t)gm * N + gn] =
                        f2b(0.5f * v * (1.0f + erff(v * 0.70710678118654752f)));
                }
            } else {
                #pragma unroll
                for (int ni = 0; ni < 4; ni++) {
                    int gn = tn + wn + ni * 16 + cl;
                    outf[(size_t)gm * 768 + gn] =
                        yres[(size_t)gm * 768 + gn] + acc[mi][ni][r] + bv[ni];
                }
            }
        }
    }
}

// ---------------------------------------------------------------------------
// K3: fused MFMA windowed attention, v5 = round-7 structure (K + V staged in
// LDS — proven 72 us) with LDS squeezed 77.3 -> 64.5 KB:
//  * rel tables dropped from Bs (208 rows now); their B-frags read direct
//    from the 4 KB block-invariant global tables (L1-hot, 8/62 MFMAs).
//  * relS unioned with Ps (relS dead after logit loop).
// ---------------------------------------------------------------------------
__launch_bounds__(256)
__global__ void attn_kernel(const bf16* __restrict__ qkv,
                            const bf16* __restrict__ vtg,
                            const bf16* __restrict__ bias_bf,
                            const bf16* __restrict__ rhb,
                            const bf16* __restrict__ rwb,
                            bf16* __restrict__ att)
{
    __shared__ bf16 BsLo[208 * 32];      // K rows 0..195, 196..207 zero
    __shared__ bf16 BsHi[208 * 32];
    __shared__ bf16 Vt[64 * 232];        // stride 232, cols 196..231 zero
    __shared__ bf16 un[4][1024];         // union: relS[t*512+row*32+idx] / Ps[row*36+col]

    int bh = blockIdx.x;
    int bwi = bh / 12, head = bh % 12;
    int tid = threadIdx.x, w = tid >> 6, lane = tid & 63;
    int b = bwi / 25, wq = bwi % 25;
    int r0 = (wq / 5) * 14, c0 = (wq % 5) * 14;

    // zero pad rows 196..207 of Bs
    for (int idx = tid; idx < 12 * 16; idx += 256) {
        int r = 196 + (idx >> 4), cd = idx & 15;
        ((unsigned*)BsLo)[r * 16 + cd] = 0u;
        ((unsigned*)BsHi)[r * 16 + cd] = 0u;
    }
    // K rows 0..195: window gather or bias
    for (int idx = tid; idx < 196 * 32; idx += 256) {
        int m = idx >> 5, c2 = idx & 31;
        int i = m / 14, j = m % 14;
        int rr = r0 + i, cc = c0 + j;
        const bf16* src = (rr < 64 && cc < 64)
            ? qkv + ((size_t)((b << 12) + rr * 64 + cc) * 2304 + 768 + head * 64)
            : bias_bf + 768 + head * 64;
        unsigned u = *(const unsigned*)(src + 2 * c2);
        if (c2 < 16) ((unsigned*)BsLo)[m * 16 + c2] = u;
        else         ((unsigned*)BsHi)[m * 16 + (c2 - 16)] = u;
    }
    // Vt: zero cols 196..231, stage keys 0..195 from vtg (196-stride)
    for (int idx = tid; idx < 64 * 18; idx += 256) {
        int d = idx / 18, cd = idx % 18;
        ((unsigned*)Vt)[d * 116 + 98 + cd] = 0u;
    }
    {
        const bf16* vrow = vtg + (size_t)(bwi * 12 + head) * 64 * 196;
        for (int idx = tid; idx < 64 * 98; idx += 256) {
            int d = idx / 98, kp = idx % 98;
            ((unsigned*)Vt)[d * 116 + kp] = *(const unsigned*)(vrow + (size_t)d * 196 + 2 * kp);
        }
    }
    __syncthreads();

    const int cl = lane & 15, rg = lane >> 4;
    const int lr0 = rg * 4;

    for (int mt = w; mt < 13; mt += 4) {
        int q0 = mt * 16 + cl;
        int qi = q0 / 14, qj = q0 % 14;
        int qr = r0 + qi, qc = c0 + qj;
        bool qv = (q0 < 196) && (qr < 64) && (qc < 64);
        const bf16* qp = qv
            ? qkv + ((size_t)((b << 12) + qr * 64 + qc) * 2304 + head * 64 + rg * 8)
            : bias_bf + head * 64 + rg * 8;
        short8 af0 = *(const short8*)(qp);
        short8 af1 = *(const short8*)(qp + 32);

        f32x4 sc[17];
        // table tiles direct from global first (latency overlapped by K tiles)
        #pragma unroll
        for (int t2 = 0; t2 < 2; t2++) {
            const bf16* hp = rhb + (t2 * 16 + cl) * 64;
            f32x4 th = {};
            th = __builtin_amdgcn_mfma_f32_16x16x32_bf16(
                af0, *(const short8*)(hp + rg * 8), th, 0, 0, 0);
            sc[13 + t2] = __builtin_amdgcn_mfma_f32_16x16x32_bf16(
                af1, *(const short8*)(hp + 32 + rg * 8), th, 0, 0, 0);
            const bf16* wp2 = rwb + (t2 * 16 + cl) * 64;
            f32x4 tw = {};
            tw = __builtin_amdgcn_mfma_f32_16x16x32_bf16(
                af0, *(const short8*)(wp2 + rg * 8), tw, 0, 0, 0);
            sc[15 + t2] = __builtin_amdgcn_mfma_f32_16x16x32_bf16(
                af1, *(const short8*)(wp2 + 32 + rg * 8), tw, 0, 0, 0);
        }
        #pragma unroll
        for (int ni = 0; ni < 13; ni++) {
            short8 blo = *(const short8*)(BsLo + (ni * 16 + cl) * 32 + rg * 8);
            short8 bhi = *(const short8*)(BsHi + (ni * 16 + cl) * 32 + rg * 8);
            f32x4 t = {};
            t = __builtin_amdgcn_mfma_f32_16x16x32_bf16(af0, blo, t, 0, 0, 0);
            sc[ni] = __builtin_amdgcn_mfma_f32_16x16x32_bf16(af1, bhi, t, 0, 0, 0);
        }
        // rel tiles -> LDS union (relS region)
        #pragma unroll
        for (int t2 = 0; t2 < 2; t2++)
            #pragma unroll
            for (int r = 0; r < 4; r++) {
                un[w][(lr0 + r) * 32 + t2 * 16 + cl]       = f2b(sc[13 + t2][r]);
                un[w][512 + (lr0 + r) * 32 + t2 * 16 + cl] = f2b(sc[15 + t2][r]);
            }
        __builtin_amdgcn_wave_barrier();

        int iq[4], jq[4];
        #pragma unroll
        for (int r = 0; r < 4; r++) { int q = mt * 16 + lr0 + r; iq[r] = q / 14; jq[r] = q % 14; }
        float mx[4] = { -1e30f, -1e30f, -1e30f, -1e30f };
        #pragma unroll
        for (int ni = 0; ni < 13; ni++) {
            int c = ni * 16 + cl;
            int kh = c / 14; if (kh > 13) kh = 13;
            int kw = c - (c / 14) * 14;
            bool valid = c < 196;
            #pragma unroll
            for (int r = 0; r < 4; r++) {
                float lg = sc[ni][r] * 0.125f
                         + b2f(un[w][(lr0 + r) * 32 + iq[r] - kh + 13])
                         + b2f(un[w][512 + (lr0 + r) * 32 + jq[r] - kw + 13]);
                sc[ni][r] = valid ? lg : -1e30f;
                mx[r] = fmaxf(mx[r], sc[ni][r]);
            }
        }
        float sum[4];
        #pragma unroll
        for (int r = 0; r < 4; r++) {
            #pragma unroll
            for (int o = 1; o < 16; o <<= 1) mx[r] = fmaxf(mx[r], __shfl_xor(mx[r], o));
            sum[r] = 0.f;
        }
        #pragma unroll
        for (int ni = 0; ni < 13; ni++)
            #pragma unroll
            for (int r = 0; r < 4; r++) {
                float e = __expf(sc[ni][r] - mx[r]);
                sc[ni][r] = e; sum[r] += e;
            }
        #pragma unroll
        for (int r = 0; r < 4; r++) {
            #pragma unroll
            for (int o = 1; o < 16; o <<= 1) sum[r] += __shfl_xor(sum[r], o);
            sum[r] = 1.0f / sum[r];
        }
        __builtin_amdgcn_wave_barrier();   // relS reads complete before Ps writes

        // PV: P slices through the union's Ps region; V from LDS Vt
        f32x4 ov[4] = {};
        #pragma unroll
        for (int ks = 0; ks < 7; ks++) {
            #pragma unroll
            for (int r = 0; r < 4; r++) {
                un[w][(lr0 + r) * 36 + cl] = f2b(sc[2 * ks][r] * sum[r]);
                un[w][(lr0 + r) * 36 + 16 + cl] =
                    (2 * ks + 1 < 13) ? f2b(sc[2 * ks + 1][r] * sum[r]) : f2b(0.0f);
            }
            __builtin_amdgcn_wave_barrier();
            short8 pa = *(const short8*)(&un[w][cl * 36 + rg * 8]);
            #pragma unroll
            for (int ni = 0; ni < 4; ni++) {
                short8 vb = *(const short8*)(Vt + (ni * 16 + cl) * 232 + ks * 32 + rg * 8);
                ov[ni] = __builtin_amdgcn_mfma_f32_16x16x32_bf16(pa, vb, ov[ni], 0, 0, 0);
            }
            __builtin_amdgcn_wave_barrier();
        }

        #pragma unroll
        for (int r = 0; r < 4; r++) {
            int q = mt * 16 + lr0 + r;
            int i = q / 14, j = q % 14;
            int rr = r0 + i, cc = c0 + j;
            if (q < 196 && rr < 64 && cc < 64) {
                size_t ob = (size_t)((b << 12) + rr * 64 + cc) * 768 + head * 64;
                #pragma unroll
                for (int ni = 0; ni < 4; ni++)
                    att[ob + ni * 16 + cl] = f2b(ov[ni][r]);
            }
        }
    }
}

// ---------------------------------------------------------------------------
// Workspace (MiB offsets, peak ~104 MiB):
//   0 qkv_wt | 3.5 proj_wt | 5 fc1_wt | 10 fc2_wt
//   14.5 bias_bf | 14.75 rhb (4K) | 14.75+4K rwb (4K)
//   15 xn1/att/xn2 | 28 qkvb (37.7M) / later h (50.3M)
//   64 vt 50x12x64x196 bf16 (14.4M) | 79 y 8192x768 f32 (25.2M)
// ---------------------------------------------------------------------------
extern "C" void kernel_launch(void* const* d_in, const int* in_sizes, int n_in,
                              void* d_out, int out_size, void* d_ws, size_t ws_size,
                              hipStream_t stream)
{
    const float* x      = (const float*)d_in[0];
    const float* n1w    = (const float*)d_in[1];
    const float* n1b    = (const float*)d_in[2];
    const float* qkv_w  = (const float*)d_in[3];
    const float* qkv_b  = (const float*)d_in[4];
    const float* proj_w = (const float*)d_in[5];
    const float* proj_b = (const float*)d_in[6];
    const float* rph    = (const float*)d_in[7];
    const float* rpw    = (const float*)d_in[8];
    const float* n2w    = (const float*)d_in[9];
    const float* n2b    = (const float*)d_in[10];
    const float* fc1_w  = (const float*)d_in[11];
    const float* fc1_b  = (const float*)d_in[12];
    const float* fc2_w  = (const float*)d_in[13];
    const float* fc2_b  = (const float*)d_in[14];
    float* out = (float*)d_out;

    char* ws = (char*)d_ws;
    const size_t MB = (size_t)1 << 20;
    bf16* qkv_wt  = (bf16*)(ws);
    bf16* proj_wt = (bf16*)(ws + (size_t)(3.5 * MB));
    bf16* fc1_wt  = (bf16*)(ws + 5 * MB);
    bf16* fc2_wt  = (bf16*)(ws + 10 * MB);
    bf16* bias_bf = (bf16*)(ws + (size_t)(14.5 * MB));
    bf16* rhb     = (bf16*)(ws + (size_t)(14.75 * MB));
    bf16* rwb     = (bf16*)(ws + (size_t)(14.75 * MB) + 4096);
    bf16* xn1     = (bf16*)(ws + 15 * MB);
    bf16* att     = (bf16*)(ws + 15 * MB);
    bf16* xn2     = (bf16*)(ws + 15 * MB);
    bf16* qkvb    = (bf16*)(ws + 28 * MB);
    bf16* h       = (bf16*)(ws + 28 * MB);
    bf16* vt      = (bf16*)(ws + 64 * MB);
    float* y      = (float*)(ws + 79 * MB);

    transpose_all<<<6912, 256, 0, stream>>>(qkv_w, proj_w, fc1_w, fc2_w,
                                            qkv_wt, proj_wt, fc1_wt, fc2_wt);
    fill_kernel<<<601, 256, 0, stream>>>(qkv_b, rph, rpw, vt, bias_bf, rhb, rwb);

    ln_kernel<<<8192, 256, 0, stream>>>(x, n1w, n1b, xn1);
    mfma_gemm<0, 128><<<dim3(18, 64), 256, 0, stream>>>(
        xn1, qkv_wt, qkv_b, qkvb, nullptr, nullptr, nullptr, vt, 8192, 2304, 768);
    attn_kernel<<<600, 256, 0, stream>>>(qkvb, vt, bias_bf, rhb, rwb, att);
    mfma_gemm<1, 64><<<dim3(6, 128), 256, 0, stream>>>(
        att, proj_wt, proj_b, nullptr, y, x, nullptr, nullptr, 8192, 768, 768);
    ln_kernel<<<8192, 256, 0, stream>>>(y, n2w, n2b, xn2);
    mfma_gemm<2, 128><<<dim3(24, 64), 256, 0, stream>>>(
        xn2, fc1_wt, fc1_b, h, nullptr, nullptr, nullptr, nullptr, 8192, 3072, 768);
    mfma_gemm<3, 64><<<dim3(6, 128), 256, 0, stream>>>(
        h, fc2_wt, fc2_b, nullptr, out, nullptr, y, nullptr, 8192, 768, 3072);
}

// Round 11
// 378.753 us; speedup vs baseline: 1.2147x; 1.1113x over previous
//
#include <hip/hip_runtime.h>
#include <hip/hip_bf16.h>
#include <math.h>

typedef __hip_bfloat16 bf16;
typedef __attribute__((ext_vector_type(8))) short short8;
typedef __attribute__((ext_vector_type(4))) float f32x4;

__device__ __forceinline__ float b2f(bf16 v) { return __bfloat162float(v); }
__device__ __forceinline__ bf16 f2b(float f) { return __float2bfloat16(f); }

// ---------------------------------------------------------------------------
// K0: all 4 weight transposes (fp32 KxN -> bf16 NxK) in one launch.
// ---------------------------------------------------------------------------
__launch_bounds__(256)
__global__ void transpose_all(const float* __restrict__ qkv_w,
                              const float* __restrict__ proj_w,
                              const float* __restrict__ fc1_w,
                              const float* __restrict__ fc2_w,
                              bf16* __restrict__ qkv_wt,
                              bf16* __restrict__ proj_wt,
                              bf16* __restrict__ fc1_wt,
                              bf16* __restrict__ fc2_wt)
{
    __shared__ float t[32][33];
    int id = blockIdx.x;
    const float* W; bf16* Wt; int K, N, tix, tiy;
    if (id < 1728)      { W = qkv_w;  Wt = qkv_wt;  K = 768;  N = 2304; tix = id % 72;           tiy = id / 72; }
    else if (id < 2304) { W = proj_w; Wt = proj_wt; K = 768;  N = 768;  tix = (id - 1728) % 24;  tiy = (id - 1728) / 24; }
    else if (id < 4608) { W = fc1_w;  Wt = fc1_wt;  K = 768;  N = 3072; tix = (id - 2304) % 96;  tiy = (id - 2304) / 96; }
    else                { W = fc2_w;  Wt = fc2_wt;  K = 3072; N = 768;  tix = (id - 4608) % 24;  tiy = (id - 4608) / 24; }
    int n0 = tix * 32, k0 = tiy * 32;
    int tx = threadIdx.x & 31, ty = threadIdx.x >> 5;   // 32 x 8
    #pragma unroll
    for (int i = 0; i < 4; i++)
        t[ty * 4 + i][tx] = W[(size_t)(k0 + ty * 4 + i) * N + n0 + tx];
    __syncthreads();
    #pragma unroll
    for (int i = 0; i < 4; i++)
        Wt[(size_t)(n0 + ty * 4 + i) * K + k0 + tx] = f2b(t[tx][ty * 4 + i]);
}

// ---------------------------------------------------------------------------
// K0b: vt (232-stride) pad-fill: keys 196..231 zero for all rows; padded-
// window keys get v_bias. Convert qkv_b -> bf16; build bf16 rel tables
// (32 x 64, rows >= 27 zero).
// ---------------------------------------------------------------------------
__launch_bounds__(256)
__global__ void fill_kernel(const float* __restrict__ qkv_b,
                            const float* __restrict__ rel_h,
                            const float* __restrict__ rel_w,
                            bf16* __restrict__ vt,
                            bf16* __restrict__ bias_bf,
                            bf16* __restrict__ rhb,
                            bf16* __restrict__ rwb)
{
    int blk = blockIdx.x;
    int tid = threadIdx.x;
    if (blk == 600) {
        for (int c = tid; c < 2304; c += 256) bias_bf[c] = f2b(qkv_b[c]);
        for (int idx = tid; idx < 2048; idx += 256) {
            int r = idx >> 6, c = idx & 63;
            rhb[idx] = (r < 27) ? f2b(rel_h[r * 64 + c]) : f2b(0.0f);
            rwb[idx] = (r < 27) ? f2b(rel_w[r * 64 + c]) : f2b(0.0f);
        }
        return;
    }
    int bwi = blk / 12, head = blk % 12;
    size_t base = (size_t)(bwi * 12 + head) * 64 * 232;
    // zero keys 196..231 for all d rows
    for (int t = tid; t < 64 * 36; t += 256) {
        int d = t / 36, k = 196 + t % 36;
        vt[base + (size_t)d * 232 + k] = f2b(0.0f);
    }
    int wq = bwi % 25;
    int hi = ((wq / 5) == 4) ? 8 : 14;
    int wi = ((wq % 5) == 4) ? 8 : 14;
    if (hi == 14 && wi == 14) return;
    for (int t = tid; t < 196 * 64; t += 256) {
        int d = t & 63, key = t >> 6;
        int i = key / 14, j = key % 14;
        if (i >= hi || j >= wi)
            vt[base + (size_t)d * 232 + key] = f2b(qkv_b[1536 + head * 64 + d]);
    }
}

// ---------------------------------------------------------------------------
// K1/K5: LayerNorm (fp32 in, 768 cols) -> bf16 out.
// ---------------------------------------------------------------------------
__launch_bounds__(256)
__global__ void ln_kernel(const float* __restrict__ y,
                          const float* __restrict__ wgt,
                          const float* __restrict__ bia,
                          bf16* __restrict__ xn)
{
    int blk = blockIdx.x;
    const float* yin = y + (size_t)blk * 768;
    bf16* out = xn + (size_t)blk * 768;
    int tid = threadIdx.x;
    float v[3]; float s = 0.f, ss = 0.f;
    #pragma unroll
    for (int t = 0; t < 3; t++) {
        float f = yin[tid + t * 256];
        v[t] = f; s += f; ss += f * f;
    }
    #pragma unroll
    for (int o = 32; o > 0; o >>= 1) { s += __shfl_xor(s, o); ss += __shfl_xor(ss, o); }
    __shared__ float red[8];
    int w = tid >> 6, lane = tid & 63;
    if (lane == 0) { red[w] = s; red[4 + w] = ss; }
    __syncthreads();
    s  = red[0] + red[1] + red[2] + red[3];
    ss = red[4] + red[5] + red[6] + red[7];
    float mu = s * (1.0f / 768.0f);
    float var = ss * (1.0f / 768.0f) - mu * mu;
    float rs = rsqrtf(var + 1e-5f);
    #pragma unroll
    for (int t = 0; t < 3; t++) {
        int c = tid + t * 256;
        out[c] = f2b((v[t] - mu) * rs * wgt[c] + bia[c]);
    }
}

// ---------------------------------------------------------------------------
// MFMA GEMM: C = A(M x K) @ Bt^T + bias.  BK=64 (two BK=32 LDS buffers),
// XCD-aware swizzle.  EPI 0 V-scatter now writes 232-stride vt.
// ---------------------------------------------------------------------------
template<int EPI, int BM>
__launch_bounds__(256)
__global__ void mfma_gemm(const bf16* __restrict__ A,
                          const bf16* __restrict__ Bt,
                          const float* __restrict__ bias,
                          bf16* __restrict__ outb,
                          float* __restrict__ outf,
                          const float* __restrict__ xres,
                          const float* __restrict__ yres,
                          bf16* __restrict__ vtg,
                          int M, int N, int K)
{
    constexpr int MI = BM / 32;
    __shared__ bf16 As0[BM * 32];
    __shared__ bf16 As1[BM * 32];
    __shared__ bf16 Bs0[128 * 32];
    __shared__ bf16 Bs1[128 * 32];
    const int tid = threadIdx.x;
    const int w = tid >> 6, lane = tid & 63;
    const int cl = lane & 15, rg = lane >> 4;
    const int wm = (w & 1) * (BM / 2), wn = (w >> 1) * 64;

    const int gx = gridDim.x;
    int f = blockIdx.x + gx * blockIdx.y;
    int g = f / (8 * gx), r8 = f % (8 * gx);
    const int tm = (g * 8 + (r8 & 7)) * BM;
    const int tn = (r8 >> 3) * 128;

    f32x4 acc[MI][4] = {};

    for (int k0 = 0; k0 < K; k0 += 64) {
        #pragma unroll
        for (int i = 0; i < BM / 64; i++) {
            int e = i * 256 + tid;
            int r = e >> 2, ch = e & 3;
            const bf16* ap = A + (size_t)(tm + r) * K + k0 + ch * 8;
            __builtin_amdgcn_global_load_lds(
                (const __attribute__((address_space(1))) unsigned*)(ap),
                (__attribute__((address_space(3))) unsigned*)(As0 + e * 8), 16, 0, 0);
            __builtin_amdgcn_global_load_lds(
                (const __attribute__((address_space(1))) unsigned*)(ap + 32),
                (__attribute__((address_space(3))) unsigned*)(As1 + e * 8), 16, 0, 0);
        }
        #pragma unroll
        for (int i = 0; i < 2; i++) {
            int e = i * 256 + tid;
            int r = e >> 2, ch = e & 3;
            const bf16* bp = Bt + (size_t)(tn + r) * K + k0 + ch * 8;
            __builtin_amdgcn_global_load_lds(
                (const __attribute__((address_space(1))) unsigned*)(bp),
                (__attribute__((address_space(3))) unsigned*)(Bs0 + e * 8), 16, 0, 0);
            __builtin_amdgcn_global_load_lds(
                (const __attribute__((address_space(1))) unsigned*)(bp + 32),
                (__attribute__((address_space(3))) unsigned*)(Bs1 + e * 8), 16, 0, 0);
        }
        __syncthreads();
        #pragma unroll
        for (int kk = 0; kk < 2; kk++) {
            const bf16* Ab = kk ? As1 : As0;
            const bf16* Bb = kk ? Bs1 : Bs0;
            short8 af[MI], bfr[4];
            #pragma unroll
            for (int mi = 0; mi < MI; mi++)
                af[mi] = *(const short8*)(Ab + (wm + mi * 16 + cl) * 32 + rg * 8);
            #pragma unroll
            for (int ni = 0; ni < 4; ni++)
                bfr[ni] = *(const short8*)(Bb + (wn + ni * 16 + cl) * 32 + rg * 8);
            #pragma unroll
            for (int mi = 0; mi < MI; mi++)
                #pragma unroll
                for (int ni = 0; ni < 4; ni++)
                    acc[mi][ni] = __builtin_amdgcn_mfma_f32_16x16x32_bf16(
                        af[mi], bfr[ni], acc[mi][ni], 0, 0, 0);
        }
        __syncthreads();
    }

    const int row_l = rg * 4;
    float bv[4];
    #pragma unroll
    for (int ni = 0; ni < 4; ni++) bv[ni] = bias[tn + wn + ni * 16 + cl];

    #pragma unroll
    for (int mi = 0; mi < MI; mi++) {
        #pragma unroll
        for (int r = 0; r < 4; r++) {
            int gm = tm + wm + mi * 16 + row_l + r;
            if (EPI == 0) {
                int bb = gm >> 12, rr = (gm >> 6) & 63, cc = gm & 63;
                int wh = rr / 14, ii = rr - wh * 14;
                int ww2 = cc / 14, jj = cc - ww2 * 14;
                size_t vrow = (size_t)((bb * 25 + wh * 5 + ww2) * 12) * 64;
                int key = ii * 14 + jj;
                #pragma unroll
                for (int ni = 0; ni < 4; ni++) {
                    int gn = tn + wn + ni * 16 + cl;
                    float v = acc[mi][ni][r] + bv[ni];
                    if (gn < 1536) {
                        outb[(size_t)gm * 2304 + gn] = f2b(v);
                    } else {
                        int hv = gn - 1536;
                        vtg[(vrow + ((hv >> 6) * 64 + (hv & 63))) * 232 + key] = f2b(v);
                    }
                }
            } else if (EPI == 1) {
                #pragma unroll
                for (int ni = 0; ni < 4; ni++) {
                    int gn = tn + wn + ni * 16 + cl;
                    outf[(size_t)gm * 768 + gn] =
                        xres[(size_t)gm * 768 + gn] + acc[mi][ni][r] + bv[ni];
                }
            } else if (EPI == 2) {
                #pragma unroll
                for (int ni = 0; ni < 4; ni++) {
                    int gn = tn + wn + ni * 16 + cl;
                    float v = acc[mi][ni][r] + bv[ni];
                    outb[(size_t)gm * N + gn] =
                        f2b(0.5f * v * (1.0f + erff(v * 0.70710678118654752f)));
                }
            } else {
                #pragma unroll
                for (int ni = 0; ni < 4; ni++) {
                    int gn = tn + wn + ni * 16 + cl;
                    outf[(size_t)gm * 768 + gn] =
                        yres[(size_t)gm * 768 + gn] + acc[mi][ni][r] + bv[ni];
                }
            }
        }
    }
}

// ---------------------------------------------------------------------------
// K3: fused MFMA windowed attention, v6 = exact r7 main loop (all MFMA
// operands from LDS — proven 72 us) with ALL staging converted to
// global_load_lds width=16 (no VGPR round-trip, no ds_writes):
//  * Bs (272 rows: K 0..195 gathered per-lane w/ bias fallback, 196..207
//    don't-care (bias row, masked in softmax), 208..239 Rh, 240..271 Rw):
//    17 wave-ops per 32B-half.
//  * Vt: linear 29 KB copy from the pre-padded 232-stride vtg: 29 wave-ops.
// LDS 77312 B (r7-proven size).
// ---------------------------------------------------------------------------
__launch_bounds__(256)
__global__ void attn_kernel(const bf16* __restrict__ qkv,
                            const bf16* __restrict__ vtg,
                            const bf16* __restrict__ bias_bf,
                            const bf16* __restrict__ rhb,
                            const bf16* __restrict__ rwb,
                            bf16* __restrict__ att)
{
    __shared__ bf16 BsLo[272 * 32];
    __shared__ bf16 BsHi[272 * 32];
    __shared__ bf16 Vt[64 * 232];
    __shared__ bf16 Ps[4][16 * 36];
    __shared__ bf16 relS[4][2][16 * 32];

    int bh = blockIdx.x;
    int bwi = bh / 12, head = bh % 12;
    int tid = threadIdx.x, w = tid >> 6, lane = tid & 63;
    int b = bwi / 25, wq = bwi % 25;
    int r0 = (wq / 5) * 14, c0 = (wq % 5) * 14;

    // Bs staging: wave-op t covers rows t*16..t*16+15, 4 chunks of 16B each.
    for (int t = w; t < 17; t += 4) {
        int m = t * 16 + (lane >> 2);
        int c = lane & 3;
        const bf16* rp;
        if (m < 208) {
            int i = m / 14, j = m - i * 14;
            int rr = r0 + i, cc = c0 + j;
            rp = (rr < 64 && cc < 64)
               ? qkv + ((size_t)((b << 12) + rr * 64 + cc) * 2304 + 768 + head * 64)
               : bias_bf + 768 + head * 64;
        } else if (m < 240) {
            rp = rhb + (m - 208) * 64;
        } else {
            rp = rwb + (m - 240) * 64;
        }
        __builtin_amdgcn_global_load_lds(
            (const __attribute__((address_space(1))) unsigned*)(rp + c * 8),
            (__attribute__((address_space(3))) unsigned*)(BsLo + t * 512 + lane * 8),
            16, 0, 0);
        __builtin_amdgcn_global_load_lds(
            (const __attribute__((address_space(1))) unsigned*)(rp + 32 + c * 8),
            (__attribute__((address_space(3))) unsigned*)(BsHi + t * 512 + lane * 8),
            16, 0, 0);
    }
    // Vt: linear copy (64 x 232 bf16 = 29696 B = 29 wave-ops)
    {
        const bf16* vsrc = vtg + (size_t)(bwi * 12 + head) * 64 * 232;
        for (int t = w; t < 29; t += 4)
            __builtin_amdgcn_global_load_lds(
                (const __attribute__((address_space(1))) unsigned*)(vsrc + t * 512 + lane * 8),
                (__attribute__((address_space(3))) unsigned*)(Vt + t * 512 + lane * 8),
                16, 0, 0);
    }
    __syncthreads();   // drains vmcnt (global_load_lds) before any LDS read

    const int cl = lane & 15, rg = lane >> 4;
    const int lr0 = rg * 4;

    for (int mt = w; mt < 13; mt += 4) {
        int q0 = mt * 16 + cl;
        int qi = q0 / 14, qj = q0 % 14;
        int qr = r0 + qi, qc = c0 + qj;
        bool qv = (q0 < 196) && (qr < 64) && (qc < 64);
        const bf16* qp = qv
            ? qkv + ((size_t)((b << 12) + qr * 64 + qc) * 2304 + head * 64 + rg * 8)
            : bias_bf + head * 64 + rg * 8;
        short8 af0 = *(const short8*)(qp);
        short8 af1 = *(const short8*)(qp + 32);

        f32x4 sc[17];
        #pragma unroll
        for (int ni = 0; ni < 17; ni++) {
            short8 blo = *(const short8*)(BsLo + (ni * 16 + cl) * 32 + rg * 8);
            short8 bhi = *(const short8*)(BsHi + (ni * 16 + cl) * 32 + rg * 8);
            f32x4 t = {};
            t = __builtin_amdgcn_mfma_f32_16x16x32_bf16(af0, blo, t, 0, 0, 0);
            sc[ni] = __builtin_amdgcn_mfma_f32_16x16x32_bf16(af1, bhi, t, 0, 0, 0);
        }
        #pragma unroll
        for (int t2 = 0; t2 < 2; t2++)
            #pragma unroll
            for (int r = 0; r < 4; r++) {
                relS[w][0][(lr0 + r) * 32 + t2 * 16 + cl] = f2b(sc[13 + t2][r]);
                relS[w][1][(lr0 + r) * 32 + t2 * 16 + cl] = f2b(sc[15 + t2][r]);
            }
        __builtin_amdgcn_wave_barrier();

        int iq[4], jq[4];
        #pragma unroll
        for (int r = 0; r < 4; r++) { int q = mt * 16 + lr0 + r; iq[r] = q / 14; jq[r] = q % 14; }
        float mx[4] = { -1e30f, -1e30f, -1e30f, -1e30f };
        #pragma unroll
        for (int ni = 0; ni < 13; ni++) {
            int c = ni * 16 + cl;
            int kh = c / 14; if (kh > 13) kh = 13;
            int kw = c - (c / 14) * 14;
            bool valid = c < 196;
            #pragma unroll
            for (int r = 0; r < 4; r++) {
                float lg = sc[ni][r] * 0.125f
                         + b2f(relS[w][0][(lr0 + r) * 32 + iq[r] - kh + 13])
                         + b2f(relS[w][1][(lr0 + r) * 32 + jq[r] - kw + 13]);
                sc[ni][r] = valid ? lg : -1e30f;
                mx[r] = fmaxf(mx[r], sc[ni][r]);
            }
        }
        float sum[4];
        #pragma unroll
        for (int r = 0; r < 4; r++) {
            #pragma unroll
            for (int o = 1; o < 16; o <<= 1) mx[r] = fmaxf(mx[r], __shfl_xor(mx[r], o));
            sum[r] = 0.f;
        }
        #pragma unroll
        for (int ni = 0; ni < 13; ni++)
            #pragma unroll
            for (int r = 0; r < 4; r++) {
                float e = __expf(sc[ni][r] - mx[r]);
                sc[ni][r] = e; sum[r] += e;
            }
        #pragma unroll
        for (int r = 0; r < 4; r++) {
            #pragma unroll
            for (int o = 1; o < 16; o <<= 1) sum[r] += __shfl_xor(sum[r], o);
            sum[r] = 1.0f / sum[r];
        }

        f32x4 ov[4] = {};
        #pragma unroll
        for (int ks = 0; ks < 7; ks++) {
            #pragma unroll
            for (int r = 0; r < 4; r++) {
                Ps[w][(lr0 + r) * 36 + cl] = f2b(sc[2 * ks][r] * sum[r]);
                Ps[w][(lr0 + r) * 36 + 16 + cl] =
                    (2 * ks + 1 < 13) ? f2b(sc[2 * ks + 1][r] * sum[r]) : f2b(0.0f);
            }
            __builtin_amdgcn_wave_barrier();
            short8 pa = *(const short8*)(&Ps[w][cl * 36 + rg * 8]);
            #pragma unroll
            for (int ni = 0; ni < 4; ni++) {
                short8 vb = *(const short8*)(Vt + (ni * 16 + cl) * 232 + ks * 32 + rg * 8);
                ov[ni] = __builtin_amdgcn_mfma_f32_16x16x32_bf16(pa, vb, ov[ni], 0, 0, 0);
            }
            __builtin_amdgcn_wave_barrier();
        }

        #pragma unroll
        for (int r = 0; r < 4; r++) {
            int q = mt * 16 + lr0 + r;
            int i = q / 14, j = q % 14;
            int rr = r0 + i, cc = c0 + j;
            if (q < 196 && rr < 64 && cc < 64) {
                size_t ob = (size_t)((b << 12) + rr * 64 + cc) * 768 + head * 64;
                #pragma unroll
                for (int ni = 0; ni < 4; ni++)
                    att[ob + ni * 16 + cl] = f2b(ov[ni][r]);
            }
        }
    }
}

// ---------------------------------------------------------------------------
// Workspace (MiB offsets, peak ~107 MiB; >=117 proven usable):
//   0 qkv_wt | 3.5 proj_wt | 5 fc1_wt | 10 fc2_wt
//   14.5 bias_bf | 14.75 rhb (4K) | 14.75+4K rwb (4K)
//   15 xn1/att/xn2 | 28 qkvb (37.7M) / later h (50.3M)
//   64 vt 600x64x232 bf16 (17.0M) | 82 y 8192x768 f32 (25.2M)
// ---------------------------------------------------------------------------
extern "C" void kernel_launch(void* const* d_in, const int* in_sizes, int n_in,
                              void* d_out, int out_size, void* d_ws, size_t ws_size,
                              hipStream_t stream)
{
    const float* x      = (const float*)d_in[0];
    const float* n1w    = (const float*)d_in[1];
    const float* n1b    = (const float*)d_in[2];
    const float* qkv_w  = (const float*)d_in[3];
    const float* qkv_b  = (const float*)d_in[4];
    const float* proj_w = (const float*)d_in[5];
    const float* proj_b = (const float*)d_in[6];
    const float* rph    = (const float*)d_in[7];
    const float* rpw    = (const float*)d_in[8];
    const float* n2w    = (const float*)d_in[9];
    const float* n2b    = (const float*)d_in[10];
    const float* fc1_w  = (const float*)d_in[11];
    const float* fc1_b  = (const float*)d_in[12];
    const float* fc2_w  = (const float*)d_in[13];
    const float* fc2_b  = (const float*)d_in[14];
    float* out = (float*)d_out;

    char* ws = (char*)d_ws;
    const size_t MB = (size_t)1 << 20;
    bf16* qkv_wt  = (bf16*)(ws);
    bf16* proj_wt = (bf16*)(ws + (size_t)(3.5 * MB));
    bf16* fc1_wt  = (bf16*)(ws + 5 * MB);
    bf16* fc2_wt  = (bf16*)(ws + 10 * MB);
    bf16* bias_bf = (bf16*)(ws + (size_t)(14.5 * MB));
    bf16* rhb     = (bf16*)(ws + (size_t)(14.75 * MB));
    bf16* rwb     = (bf16*)(ws + (size_t)(14.75 * MB) + 4096);
    bf16* xn1     = (bf16*)(ws + 15 * MB);
    bf16* att     = (bf16*)(ws + 15 * MB);
    bf16* xn2     = (bf16*)(ws + 15 * MB);
    bf16* qkvb    = (bf16*)(ws + 28 * MB);
    bf16* h       = (bf16*)(ws + 28 * MB);
    bf16* vt      = (bf16*)(ws + 64 * MB);
    float* y      = (float*)(ws + 82 * MB);

    transpose_all<<<6912, 256, 0, stream>>>(qkv_w, proj_w, fc1_w, fc2_w,
                                            qkv_wt, proj_wt, fc1_wt, fc2_wt);
    fill_kernel<<<601, 256, 0, stream>>>(qkv_b, rph, rpw, vt, bias_bf, rhb, rwb);

    ln_kernel<<<8192, 256, 0, stream>>>(x, n1w, n1b, xn1);
    mfma_gemm<0, 128><<<dim3(18, 64), 256, 0, stream>>>(
        xn1, qkv_wt, qkv_b, qkvb, nullptr, nullptr, nullptr, vt, 8192, 2304, 768);
    attn_kernel<<<600, 256, 0, stream>>>(qkvb, vt, bias_bf, rhb, rwb, att);
    mfma_gemm<1, 64><<<dim3(6, 128), 256, 0, stream>>>(
        att, proj_wt, proj_b, nullptr, y, x, nullptr, nullptr, 8192, 768, 768);
    ln_kernel<<<8192, 256, 0, stream>>>(y, n2w, n2b, xn2);
    mfma_gemm<2, 128><<<dim3(24, 64), 256, 0, stream>>>(
        xn2, fc1_wt, fc1_b, h, nullptr, nullptr, nullptr, nullptr, 8192, 3072, 768);
    mfma_gemm<3, 64><<<dim3(6, 128), 256, 0, stream>>>(
        h, fc2_wt, fc2_b, nullptr, out, nullptr, y, nullptr, 8192, 768, 3072);
}